// Round 2
// baseline (197.860 us; speedup 1.0000x reference)
//
#include <hip/hip_runtime.h>
#include <hip/hip_bf16.h>
#include <math.h>

// VectorQuantizer: z [65536 x 64] fp32, codebook [1024 x 64] fp32.
// Reference (fp32): dist = (||z||^2 - 2 z.e) + ||e||^2, argmin_k, first-occurrence ties.
// KEY NUMERIC: ||z||^2 ~ 64 absorbs the O(1e-2) differences -> dist quantized to
// ulp(64)=7.6e-6, creating ties np.argmin breaks by lowest k. We REPLICATE the
// fp32 rounding chain (numpy pairwise sum for S, exact (S - 2d) + cn order,
// no contraction) instead of computing accurately.
//
// Decomposition: 4 lane-slices per row (k % 4 == s), 2 rows per thread ->
// 131072 threads. Codebook tiles in LDS (128 codes, NPAD=68 keeps 16B align;
// within a wave the 16 row-groups broadcast-read the same address).

#define D        64
#define K        1024
#define TILE     128
#define NPAD     68
#define BLOCK    256
#define ROWS_PER_BLOCK 128

// numpy pairwise sum (n=64 path): 8 stride-8 accumulators of fl(x_j^2),
// tree combine ((r0+r1)+(r2+r3))+((r4+r5)+(r6+r7)); all rounds explicit.
__device__ __forceinline__ float np_sumsq64(const float* x) {
    float r[8];
#pragma unroll
    for (int l = 0; l < 8; ++l) r[l] = __fmul_rn(x[l], x[l]);
#pragma unroll
    for (int i = 8; i < 64; i += 8)
#pragma unroll
        for (int l = 0; l < 8; ++l)
            r[l] = __fadd_rn(r[l], __fmul_rn(x[i + l], x[i + l]));
    return __fadd_rn(__fadd_rn(__fadd_rn(r[0], r[1]), __fadd_rn(r[2], r[3])),
                     __fadd_rn(__fadd_rn(r[4], r[5]), __fadd_rn(r[6], r[7])));
}

__global__ void vq_cnorm_kernel(const float* __restrict__ cb, float* __restrict__ cn) {
    int k = blockIdx.x * blockDim.x + threadIdx.x;
    if (k >= K) return;
    float a[64];
    const float4* row = (const float4*)(cb + k * D);
#pragma unroll
    for (int j = 0; j < 16; ++j) {
        float4 v = row[j];
        a[4 * j] = v.x; a[4 * j + 1] = v.y; a[4 * j + 2] = v.z; a[4 * j + 3] = v.w;
    }
    cn[k] = np_sumsq64(a);
}

__global__ __launch_bounds__(BLOCK, 3) void vq_main_kernel(
    const float* __restrict__ z, const float* __restrict__ cb,
    const float* __restrict__ cn, float* __restrict__ zq,
    float* __restrict__ idx_out) {
    __shared__ float se[TILE * NPAD];
    __shared__ float scn[TILE];

    const int tid = threadIdx.x;
    const int s   = tid & 3;
    const int rg  = tid >> 2;
    const int r0  = blockIdx.x * ROWS_PER_BLOCK + rg;
    const int r1  = r0 + 64;

    float z0r[64], z1r[64];
    const float4* z0p = (const float4*)(z + (long)r0 * D);
    const float4* z1p = (const float4*)(z + (long)r1 * D);
#pragma unroll
    for (int j = 0; j < 16; ++j) {
        float4 a = z0p[j];
        z0r[4 * j] = a.x; z0r[4 * j + 1] = a.y; z0r[4 * j + 2] = a.z; z0r[4 * j + 3] = a.w;
        float4 b = z1p[j];
        z1r[4 * j] = b.x; z1r[4 * j + 1] = b.y; z1r[4 * j + 2] = b.z; z1r[4 * j + 3] = b.w;
    }

    const float S0 = np_sumsq64(z0r);
    const float S1 = np_sumsq64(z1r);

    float best0 = INFINITY, best1 = INFINITY;
    int   bi0 = 0, bi1 = 0;

    for (int t = 0; t < K / TILE; ++t) {
        __syncthreads();
        const float4* gsrc = (const float4*)(cb + t * TILE * D);
#pragma unroll
        for (int i = 0; i < 8; ++i) {
            int idx4 = i * BLOCK + tid;
            int c  = idx4 >> 4;
            int d4 = idx4 & 15;
            float4 v = gsrc[idx4];
            *((float4*)(se + c * NPAD + d4 * 4)) = v;
        }
        if (tid < TILE) scn[tid] = cn[t * TILE + tid];
        __syncthreads();

        for (int m = 0; m < TILE / 4; ++m) {
            const int c = 4 * m + s;
            const float4* ep = (const float4*)(se + c * NPAD);
            float d0 = 0.f, d1 = 0.f;
#pragma unroll
            for (int j = 0; j < 16; ++j) {
                float4 e = ep[j];
                d0 = fmaf(e.x, z0r[4 * j],     d0);
                d0 = fmaf(e.y, z0r[4 * j + 1], d0);
                d0 = fmaf(e.z, z0r[4 * j + 2], d0);
                d0 = fmaf(e.w, z0r[4 * j + 3], d0);
                d1 = fmaf(e.x, z1r[4 * j],     d1);
                d1 = fmaf(e.y, z1r[4 * j + 1], d1);
                d1 = fmaf(e.z, z1r[4 * j + 2], d1);
                d1 = fmaf(e.w, z1r[4 * j + 3], d1);
            }
            const float cnv = scn[c];
            // replicate fp32:  (S - 2*d) + cn   with explicit rounding, no fma
            const float dist0 = __fadd_rn(__fsub_rn(S0, __fmul_rn(2.0f, d0)), cnv);
            const float dist1 = __fadd_rn(__fsub_rn(S1, __fmul_rn(2.0f, d1)), cnv);
            const int k = t * TILE + c;
            if (dist0 < best0) { best0 = dist0; bi0 = k; }
            if (dist1 < best1) { best1 = dist1; bi1 = k; }
        }
    }

    // cross-slice argmin reduce within lane quad (val, then lowest index)
#pragma unroll
    for (int off = 1; off <= 2; off <<= 1) {
        float ov0 = __shfl_xor(best0, off);
        int   oi0 = __shfl_xor(bi0,   off);
        if (ov0 < best0 || (ov0 == best0 && oi0 < bi0)) { best0 = ov0; bi0 = oi0; }
        float ov1 = __shfl_xor(best1, off);
        int   oi1 = __shfl_xor(bi1,   off);
        if (ov1 < best1 || (ov1 == best1 && oi1 < bi1)) { best1 = ov1; bi1 = oi1; }
    }

    if (s == 0) {
        idx_out[r0] = (float)bi0;
        idx_out[r1] = (float)bi1;
    }

    const float4* c0 = (const float4*)(cb + (long)bi0 * D);
    const float4* c1 = (const float4*)(cb + (long)bi1 * D);
    float4* o0 = (float4*)(zq + (long)r0 * D);
    float4* o1 = (float4*)(zq + (long)r1 * D);
#pragma unroll
    for (int j = 0; j < 4; ++j) {
        o0[s * 4 + j] = c0[s * 4 + j];
        o1[s * 4 + j] = c1[s * 4 + j];
    }
}

extern "C" void kernel_launch(void* const* d_in, const int* in_sizes, int n_in,
                              void* d_out, int out_size, void* d_ws, size_t ws_size,
                              hipStream_t stream) {
    const float* z  = (const float*)d_in[0];
    const float* cb = (const float*)d_in[1];
    float* cn = (float*)d_ws;

    const int n_rows = in_sizes[0] / D;
    float* zq      = (float*)d_out;
    float* idx_out = zq + (long)n_rows * D;

    vq_cnorm_kernel<<<(K + BLOCK - 1) / BLOCK, BLOCK, 0, stream>>>(cb, cn);

    const int grid = n_rows / ROWS_PER_BLOCK;
    vq_main_kernel<<<grid, BLOCK, 0, stream>>>(z, cb, cn, zq, idx_out);
}

// Round 3
// 183.033 us; speedup vs baseline: 1.0810x; 1.0810x over previous
//
#include <hip/hip_runtime.h>
#include <hip/hip_bf16.h>
#include <math.h>

// VectorQuantizer: z [65536 x 64] fp32, codebook [1024 x 64] fp32.
// dist = (||z||^2 - 2 z.e) + ||e||^2 with EXACT fp32 rounding replication
// (numpy pairwise sumsq, sequential fmaf dot, (S-2d)+cn order, no contraction),
// strict-< ascending-k argmin = np.argmin first-occurrence. R1 validated this
// numeric chain (absmax 0); this round keeps it bit-identical and fixes perf:
//
// R2 post-mortem: 8 FMA per LDS b128 read -> DS pipe 2x oversubscribed
// (VALUBusy 56%), and register-resident z was defeated by the allocator
// (VGPR=84 < 128 needed). Fix: GEMM-style tiling. Block = 128 rows x 128
// codes/tile, thread tile 8x8 -> 256 FMAs per 16 LDS reads (16 FMA/read).
// z-reads broadcast (16 lanes same addr); cb codes interleaved (c=cc*16+tcol)
// so consecutive lanes hit stride-68 rows -> 2-way bank aliasing (free).

#define D      64
#define K      1024
#define BR     128          // rows per block
#define CT     128          // codes per LDS tile
#define NT     (K / CT)     // 8 tiles
#define STR    68           // LDS row stride in floats (16B aligned, bank-shifted)
#define BLOCK  256

// numpy pairwise sum for n=64: 8 stride-8 accumulators of fl(x^2), tree combine.
__device__ __forceinline__ float np_sumsq64(const float* x) {
    float r[8];
#pragma unroll
    for (int l = 0; l < 8; ++l) r[l] = __fmul_rn(x[l], x[l]);
#pragma unroll
    for (int i = 8; i < 64; i += 8)
#pragma unroll
        for (int l = 0; l < 8; ++l)
            r[l] = __fadd_rn(r[l], __fmul_rn(x[i + l], x[i + l]));
    return __fadd_rn(__fadd_rn(__fadd_rn(r[0], r[1]), __fadd_rn(r[2], r[3])),
                     __fadd_rn(__fadd_rn(r[4], r[5]), __fadd_rn(r[6], r[7])));
}

__device__ __forceinline__ float lds_sumsq_row(const float* rp) {
    float a[64];
#pragma unroll
    for (int j = 0; j < 16; ++j) {
        float4 v = *(const float4*)(rp + j * 4);
        a[4 * j] = v.x; a[4 * j + 1] = v.y; a[4 * j + 2] = v.z; a[4 * j + 3] = v.w;
    }
    return np_sumsq64(a);
}

__global__ __launch_bounds__(BLOCK, 2) void vq_kernel(
    const float* __restrict__ z, const float* __restrict__ cb,
    float* __restrict__ zq, float* __restrict__ idx_out) {
    __shared__ float sz[BR * STR];
    __shared__ float sc[CT * STR];
    __shared__ float sS[BR];
    __shared__ float sCn[CT];

    const int tid  = threadIdx.x;
    const int tcol = tid & 15;      // code group 0..15
    const int trow = tid >> 4;      // row group 0..15
    const long base_row = (long)blockIdx.x * BR;

    // ---- stage z-tile: 2048 float4, 8 per thread, coalesced ----
    const float4* gz = (const float4*)(z + base_row * D);
#pragma unroll
    for (int i = 0; i < 8; ++i) {
        int idx4 = i * BLOCK + tid;
        int r = idx4 >> 4, d4 = idx4 & 15;
        float4 v = gz[idx4];
        *(float4*)(sz + r * STR + d4 * 4) = v;
    }
    __syncthreads();

    // ---- row norms S (np pairwise), once per block ----
    if (tid < BR) sS[tid] = lds_sumsq_row(sz + tid * STR);

    float bestv[8];
    int   besti[8];
#pragma unroll
    for (int r = 0; r < 8; ++r) { bestv[r] = INFINITY; besti[r] = 0; }
    float myS[8];

    for (int t = 0; t < NT; ++t) {
        __syncthreads();   // B1: prev epilogue done (cb/sCn free); sS visible after this
        // ---- stage cb-tile t ----
        const float4* gc = (const float4*)(cb + (long)t * CT * D);
        float4 st[8];
#pragma unroll
        for (int i = 0; i < 8; ++i) st[i] = gc[i * BLOCK + tid];
#pragma unroll
        for (int i = 0; i < 8; ++i) {
            int idx4 = i * BLOCK + tid;
            int c = idx4 >> 4, d4 = idx4 & 15;
            *(float4*)(sc + c * STR + d4 * 4) = st[i];
        }
        __syncthreads();   // B2: cb-tile visible
        // ---- code norms for this tile (np pairwise) ----
        if (tid < CT) sCn[tid] = lds_sumsq_row(sc + tid * STR);
        if (t == 0) {
#pragma unroll
            for (int r = 0; r < 8; ++r) myS[r] = sS[r * 16 + trow];
        }

        // ---- 8x8 register-tile dot accumulation over D ----
        float acc[8][8];
#pragma unroll
        for (int r = 0; r < 8; ++r)
#pragma unroll
            for (int c = 0; c < 8; ++c) acc[r][c] = 0.f;

#pragma unroll 2
        for (int j = 0; j < 16; ++j) {
            float4 zf[8], ef[8];
#pragma unroll
            for (int r = 0; r < 8; ++r)
                zf[r] = *(const float4*)(sz + (r * 16 + trow) * STR + j * 4);
#pragma unroll
            for (int c = 0; c < 8; ++c)
                ef[c] = *(const float4*)(sc + (c * 16 + tcol) * STR + j * 4);
#pragma unroll
            for (int r = 0; r < 8; ++r)
#pragma unroll
                for (int c = 0; c < 8; ++c) {
                    acc[r][c] = fmaf(zf[r].x, ef[c].x, acc[r][c]);
                    acc[r][c] = fmaf(zf[r].y, ef[c].y, acc[r][c]);
                    acc[r][c] = fmaf(zf[r].z, ef[c].z, acc[r][c]);
                    acc[r][c] = fmaf(zf[r].w, ef[c].w, acc[r][c]);
                }
        }
        __syncthreads();   // B3: sCn visible; FMA reads of sc done
        // ---- dist + argmin (ascending k per thread; strict <) ----
#pragma unroll
        for (int c = 0; c < 8; ++c) {
            const float cn = sCn[c * 16 + tcol];
            const int kidx = t * CT + c * 16 + tcol;
#pragma unroll
            for (int r = 0; r < 8; ++r) {
                const float dist =
                    __fadd_rn(__fsub_rn(myS[r], __fmul_rn(2.0f, acc[r][c])), cn);
                if (dist < bestv[r]) { bestv[r] = dist; besti[r] = kidx; }
            }
        }
    }

    // ---- cross-thread (tcol) argmin reduce + outputs ----
#pragma unroll
    for (int r = 0; r < 8; ++r) {
        float bv = bestv[r];
        int   bi = besti[r];
#pragma unroll
        for (int off = 1; off <= 8; off <<= 1) {
            float ov = __shfl_xor(bv, off);
            int   oi = __shfl_xor(bi, off);
            if (ov < bv || (ov == bv && oi < bi)) { bv = ov; bi = oi; }
        }
        const long row = base_row + r * 16 + trow;
        if (tcol == 0) idx_out[row] = (float)bi;
        float4 v = *(const float4*)(cb + (long)bi * D + tcol * 4);
        *(float4*)(zq + row * D + tcol * 4) = v;
    }
}

extern "C" void kernel_launch(void* const* d_in, const int* in_sizes, int n_in,
                              void* d_out, int out_size, void* d_ws, size_t ws_size,
                              hipStream_t stream) {
    const float* z  = (const float*)d_in[0];
    const float* cb = (const float*)d_in[1];

    const int n_rows = in_sizes[0] / D;       // 65536
    float* zq      = (float*)d_out;
    float* idx_out = zq + (long)n_rows * D;

    const int grid = n_rows / BR;             // 512
    vq_kernel<<<grid, BLOCK, 0, stream>>>(z, cb, zq, idx_out);
}

// Round 4
// 116.180 us; speedup vs baseline: 1.7030x; 1.5754x over previous
//
#include <hip/hip_runtime.h>
#include <hip/hip_bf16.h>
#include <math.h>

// VectorQuantizer: z [65536 x 64] fp32, codebook [1024 x 64] fp32.
// dist = (||z||^2 - 2 z.e) + ||e||^2, argmin_k, first-occurrence ties.
// S (row norm) and cn (code norm) use the EXACT np fp32 chains proven in
// R1/R2 (pairwise 8-acc sumsq; (S-2d)+cn with explicit __f*_rn).
// d = z.e is computed on the MATRIX pipe via f16 split-2, 3-pass MFMA:
//   a1=fl16(z), a2=fl16((z-a1)*2^11); g1=fl16(1024e), g2=fl16((1024e-g1)*2^11)
//   accM = sum a1*g1 ; accC = sum a1*g2 + a2*g1   (fp32 MFMA accum)
//   ds = fmaf(accC, 2^-11, accM) = 1024*d + O(1e-6) ; 2d = ds*2^-9 (exact)
// Error vs ref d ~ 2e-9, same order as the fmaf-chain delta that passed
// R1/R2 with absmax 0 (absorption bin ulp(S~64) = 7.6e-6).
//
// R3 was DS-pipe-bound (VALUBusy 68% == predicted 128/192). Here z(A)-frags
// are register-resident for the whole kernel; only cb(B)-frags stream from
// LDS: 0.33 b128/MFMA -> DS ~17us, MFMA ~3us, epilogue VALU ~12us (overlapped).

#define D      64
#define K      1024
#define BR     128              // rows per block
#define CT     64               // codes per tile
#define NCT    (K / CT)         // 16
#define STR32  68               // f32 LDS row stride (words)
#define STR16  72               // f16 LDS row stride (halves)
#define BLOCK  256

typedef _Float16 half8_t __attribute__((ext_vector_type(8)));
typedef _Float16 half4_t __attribute__((ext_vector_type(4)));
typedef float    floatx4 __attribute__((ext_vector_type(4)));

// numpy pairwise sumsq (n=64): 8 stride-8 accs of fl(x^2), tree combine.
// Streams 8 elements (2 float4) per i-block to keep register pressure low.
__device__ __forceinline__ float np_sumsq64_p(const float* __restrict__ x) {
    float r[8];
    {
        float4 v0 = *(const float4*)(x);
        float4 v1 = *(const float4*)(x + 4);
        r[0] = __fmul_rn(v0.x, v0.x); r[1] = __fmul_rn(v0.y, v0.y);
        r[2] = __fmul_rn(v0.z, v0.z); r[3] = __fmul_rn(v0.w, v0.w);
        r[4] = __fmul_rn(v1.x, v1.x); r[5] = __fmul_rn(v1.y, v1.y);
        r[6] = __fmul_rn(v1.z, v1.z); r[7] = __fmul_rn(v1.w, v1.w);
    }
#pragma unroll
    for (int i = 8; i < 64; i += 8) {
        float4 v0 = *(const float4*)(x + i);
        float4 v1 = *(const float4*)(x + i + 4);
        r[0] = __fadd_rn(r[0], __fmul_rn(v0.x, v0.x));
        r[1] = __fadd_rn(r[1], __fmul_rn(v0.y, v0.y));
        r[2] = __fadd_rn(r[2], __fmul_rn(v0.z, v0.z));
        r[3] = __fadd_rn(r[3], __fmul_rn(v0.w, v0.w));
        r[4] = __fadd_rn(r[4], __fmul_rn(v1.x, v1.x));
        r[5] = __fadd_rn(r[5], __fmul_rn(v1.y, v1.y));
        r[6] = __fadd_rn(r[6], __fmul_rn(v1.z, v1.z));
        r[7] = __fadd_rn(r[7], __fmul_rn(v1.w, v1.w));
    }
    return __fadd_rn(__fadd_rn(__fadd_rn(r[0], r[1]), __fadd_rn(r[2], r[3])),
                     __fadd_rn(__fadd_rn(r[4], r[5]), __fadd_rn(r[6], r[7])));
}

__global__ __launch_bounds__(BLOCK, 2) void vq_mfma_kernel(
    const float* __restrict__ z, const float* __restrict__ cb,
    float* __restrict__ zq, float* __restrict__ idx_out) {
    // zf32 (128 x 68 f32 = 34816 B) overlaid with e1/e2 (64 x 72 f16 each)
    __shared__ __align__(16) char smem[BR * STR32 * 4];
    float*    zf = (float*)smem;
    _Float16* e1 = (_Float16*)smem;
    _Float16* e2 = e1 + CT * STR16;
    __shared__ float sS[BR];
    __shared__ float sCn[CT];
    __shared__ int   sBi[BR];

    const int tid  = threadIdx.x;
    const int lane = tid & 63;
    const int wv   = tid >> 6;        // wave 0..3 -> rows wv*32..wv*32+31
    const int quad = lane >> 4;       // 0..3 (k-span / row-subgroup)
    const int l16  = lane & 15;
    const long rowbase = (long)blockIdx.x * BR;

    // ---- stage z fp32 -> LDS (coalesced) ----
    const float4* gz = (const float4*)(z + rowbase * D);
#pragma unroll
    for (int i = 0; i < 8; ++i) {
        int idx4 = i * BLOCK + tid;
        int r = idx4 >> 4, j = idx4 & 15;
        float4 v = gz[idx4];
        *(float4*)(zf + r * STR32 + j * 4) = v;
    }
    __syncthreads();

    // ---- row norms S (exact np chain) ----
    if (tid < BR) sS[tid] = np_sumsq64_p(zf + tid * STR32);

    // ---- A(z)-frags: register-resident f16 splits for this wave's 32 rows ----
    // MFMA 16x16x32 A layout: A[m=lane&15][k=quad*8+j]
    half8_t a1[2][2], a2[2][2];
#pragma unroll
    for (int rt = 0; rt < 2; ++rt) {
        const int row = wv * 32 + rt * 16 + l16;
#pragma unroll
        for (int ch = 0; ch < 2; ++ch) {
            const float* p = zf + row * STR32 + ch * 32 + quad * 8;
            float4 f0 = *(const float4*)(p);
            float4 f1 = *(const float4*)(p + 4);
            float xs[8] = {f0.x, f0.y, f0.z, f0.w, f1.x, f1.y, f1.z, f1.w};
#pragma unroll
            for (int j = 0; j < 8; ++j) {
                _Float16 h1 = (_Float16)xs[j];
                a1[rt][ch][j] = h1;
                a2[rt][ch][j] =
                    (_Float16)(__fmul_rn(__fsub_rn(xs[j], (float)h1), 2048.0f));
            }
        }
    }

    float bv[2][4];
    int   bi[2][4];
#pragma unroll
    for (int rt = 0; rt < 2; ++rt)
#pragma unroll
        for (int r = 0; r < 4; ++r) { bv[rt][r] = INFINITY; bi[rt][r] = 0; }

    for (int tI = 0; tI < NCT; ++tI) {
        const int kb = tI * CT;
        __syncthreads();  // zf/e reads of previous phase complete
        // ---- stage cb tile: fp32 -> f16 splits in LDS ----
        const float4* gcb = (const float4*)(cb + (long)kb * D);
#pragma unroll
        for (int i = 0; i < 4; ++i) {
            int idx4 = i * BLOCK + tid;
            int c = idx4 >> 4, j = idx4 & 15;
            float4 v = gcb[idx4];
            half4_t h1v, h2v;
            float xs[4] = {v.x, v.y, v.z, v.w};
#pragma unroll
            for (int q = 0; q < 4; ++q) {
                float x10 = __fmul_rn(xs[q], 1024.0f);      // exact
                _Float16 g1 = (_Float16)x10;
                h1v[q] = g1;
                h2v[q] = (_Float16)(__fmul_rn(__fsub_rn(x10, (float)g1), 2048.0f));
            }
            *(half4_t*)(e1 + c * STR16 + j * 4) = h1v;
            *(half4_t*)(e2 + c * STR16 + j * 4) = h2v;
        }
        // code norms (exact np chain, unscaled e, from L2-hot global)
        if (tid < CT) sCn[tid] = np_sumsq64_p(cb + (long)(kb + tid) * D);
        __syncthreads();

        // ---- B-frags for all 64 codes of the tile ----
        half8_t b1[4][2], b2[4][2];
#pragma unroll
        for (int ct = 0; ct < 4; ++ct) {
            const int c = ct * 16 + l16;
#pragma unroll
            for (int ch = 0; ch < 2; ++ch) {
                b1[ct][ch] = *(const half8_t*)(e1 + c * STR16 + ch * 32 + quad * 8);
                b2[ct][ch] = *(const half8_t*)(e2 + c * STR16 + ch * 32 + quad * 8);
            }
        }

#pragma unroll
        for (int rt = 0; rt < 2; ++rt) {
            floatx4 accM[4], accC[4];
#pragma unroll
            for (int ct = 0; ct < 4; ++ct) {
                accM[ct] = (floatx4){0.f, 0.f, 0.f, 0.f};
                accC[ct] = (floatx4){0.f, 0.f, 0.f, 0.f};
            }
#pragma unroll
            for (int ch = 0; ch < 2; ++ch)
#pragma unroll
                for (int ct = 0; ct < 4; ++ct) {
                    accM[ct] = __builtin_amdgcn_mfma_f32_16x16x32_f16(
                        a1[rt][ch], b1[ct][ch], accM[ct], 0, 0, 0);
                    accC[ct] = __builtin_amdgcn_mfma_f32_16x16x32_f16(
                        a1[rt][ch], b2[ct][ch], accC[ct], 0, 0, 0);
                    accC[ct] = __builtin_amdgcn_mfma_f32_16x16x32_f16(
                        a2[rt][ch], b1[ct][ch], accC[ct], 0, 0, 0);
                }
            // ---- epilogue: dist + argmin. C layout: col=lane&15, row=quad*4+reg
            float Sv[4];
#pragma unroll
            for (int r = 0; r < 4; ++r)
                Sv[r] = sS[wv * 32 + rt * 16 + quad * 4 + r];
#pragma unroll
            for (int ct = 0; ct < 4; ++ct) {
                const float cn = sCn[ct * 16 + l16];
                const int kg = kb + ct * 16 + l16;
#pragma unroll
                for (int r = 0; r < 4; ++r) {
                    float ds = fmaf(accC[ct][r], 0x1p-11f, accM[ct][r]); // 1024*d
                    float t2 = __fmul_rn(ds, 0x1p-9f);                   // 2d exact
                    float dist = __fadd_rn(__fsub_rn(Sv[r], t2), cn);
                    if (dist < bv[rt][r]) { bv[rt][r] = dist; bi[rt][r] = kg; }
                }
            }
        }
    }

    // ---- cross-lane argmin over the 16 cols (val, then lowest index) ----
#pragma unroll
    for (int rt = 0; rt < 2; ++rt) {
#pragma unroll
        for (int r = 0; r < 4; ++r) {
            float v = bv[rt][r];
            int   x = bi[rt][r];
#pragma unroll
            for (int off = 1; off <= 8; off <<= 1) {
                float ov = __shfl_xor(v, off);
                int   ox = __shfl_xor(x, off);
                if (ov < v || (ov == v && ox < x)) { v = ov; x = ox; }
            }
            if (l16 == 0) {
                const int rl = wv * 32 + rt * 16 + quad * 4 + r;
                sBi[rl] = x;
                idx_out[rowbase + rl] = (float)x;
            }
        }
    }
    __syncthreads();

    // ---- zq gather: zq[row] = cb[bi[row]] ----
    const float4* cb4 = (const float4*)cb;
    float4* zq4 = (float4*)(zq + rowbase * D);
#pragma unroll
    for (int i = 0; i < 8; ++i) {
        int idx4 = i * BLOCK + tid;
        int r = idx4 >> 4, j = idx4 & 15;
        zq4[idx4] = cb4[(long)sBi[r] * 16 + j];
    }
}

extern "C" void kernel_launch(void* const* d_in, const int* in_sizes, int n_in,
                              void* d_out, int out_size, void* d_ws, size_t ws_size,
                              hipStream_t stream) {
    const float* z  = (const float*)d_in[0];
    const float* cb = (const float*)d_in[1];

    const int n_rows = in_sizes[0] / D;       // 65536
    float* zq      = (float*)d_out;
    float* idx_out = zq + (long)n_rows * D;

    const int grid = n_rows / BR;             // 512
    vq_mfma_kernel<<<grid, BLOCK, 0, stream>>>(z, cb, zq, idx_out);
}

// Round 5
// 112.960 us; speedup vs baseline: 1.7516x; 1.0285x over previous
//
#include <hip/hip_runtime.h>
#include <hip/hip_bf16.h>
#include <math.h>

// VectorQuantizer: z [65536 x 64] fp32, codebook [1024 x 64] fp32.
// dist = (||z||^2 - 2 z.e) + ||e||^2, argmin_k, first-occurrence ties.
// Numerics identical to R4 (passed, absmax 0): exact np pairwise sumsq for
// S/cn; d via f16 split-2 3-pass MFMA (errs ~1e-8 << absorption bin 7.6e-6);
// dist = (S - 2d) + cn with explicit __f*_rn.
//
// R4 post-mortem: both pipes <25% busy — per-tile serial chain (cb load ->
// f16 split VALU -> barrier -> LDS reads -> MFMA -> epilogue) + every block
// re-splitting the codebook + 8-way-conflicted staging writes. R5: codebook
// splits+norms precomputed ONCE into d_ws in MFMA B-frag lane order; main
// loop reads frags global->VGPR (L2-resident 256 KB, coalesced 1KB/wave) —
// NO in-loop LDS, NO in-loop barriers. K split 2-ways (grid 1024); per-row
// merge via u64 atomicMin on key=(dist_bits<<32)|k (positive floats: bit-
// monotone -> lexicographic (dist, lowest k) == np.argmin tie-break).

#define D      64
#define K      1024
#define BR     128
#define BLOCK  256

typedef _Float16 half8_t __attribute__((ext_vector_type(8)));
typedef float    floatx4 __attribute__((ext_vector_type(4)));
typedef unsigned long long u64;

// ws layout
#define WS_KEYS_OFF  0            // u64[65536]          (512 KB)
#define WS_CN_OFF    524288       // float[1024]         (4 KB)
#define WS_EF_OFF    528384       // _Float16[131072]    (256 KB)
// per-tile (64 codes): 8192 halves; frag (which,ch,ct,quad,l16) at half-off
//   512*((which*2+ch)*4+ct) + 128*quad + 8*l16   (lane=quad*16+l16 -> 8*lane)

// numpy pairwise sumsq (n=64): 8 stride-8 accs of fl(x^2), tree combine.
__device__ __forceinline__ float np_sumsq64_p(const float* __restrict__ x) {
    float r[8];
    {
        float4 v0 = *(const float4*)(x);
        float4 v1 = *(const float4*)(x + 4);
        r[0] = __fmul_rn(v0.x, v0.x); r[1] = __fmul_rn(v0.y, v0.y);
        r[2] = __fmul_rn(v0.z, v0.z); r[3] = __fmul_rn(v0.w, v0.w);
        r[4] = __fmul_rn(v1.x, v1.x); r[5] = __fmul_rn(v1.y, v1.y);
        r[6] = __fmul_rn(v1.z, v1.z); r[7] = __fmul_rn(v1.w, v1.w);
    }
#pragma unroll
    for (int i = 8; i < 64; i += 8) {
        float4 v0 = *(const float4*)(x + i);
        float4 v1 = *(const float4*)(x + i + 4);
        r[0] = __fadd_rn(r[0], __fmul_rn(v0.x, v0.x));
        r[1] = __fadd_rn(r[1], __fmul_rn(v0.y, v0.y));
        r[2] = __fadd_rn(r[2], __fmul_rn(v0.z, v0.z));
        r[3] = __fadd_rn(r[3], __fmul_rn(v0.w, v0.w));
        r[4] = __fadd_rn(r[4], __fmul_rn(v1.x, v1.x));
        r[5] = __fadd_rn(r[5], __fmul_rn(v1.y, v1.y));
        r[6] = __fadd_rn(r[6], __fmul_rn(v1.z, v1.z));
        r[7] = __fadd_rn(r[7], __fmul_rn(v1.w, v1.w));
    }
    return __fadd_rn(__fadd_rn(__fadd_rn(r[0], r[1]), __fadd_rn(r[2], r[3])),
                     __fadd_rn(__fadd_rn(r[4], r[5]), __fadd_rn(r[6], r[7])));
}

// ---- precompute: code norms + f16 split-2 B-frags in MFMA lane order ----
__global__ void vq_pre(const float* __restrict__ cb, float* __restrict__ cn,
                       _Float16* __restrict__ ef) {
    const int k = blockIdx.x * 64 + threadIdx.x;
    if (k >= K) return;
    cn[k] = np_sumsq64_p(cb + (long)k * D);
    const int t = k >> 6, ct = (k >> 4) & 3, l16 = k & 15;
#pragma unroll
    for (int ch = 0; ch < 2; ++ch)
#pragma unroll
        for (int quad = 0; quad < 4; ++quad) {
            const float* p = cb + (long)k * D + ch * 32 + quad * 8;
            half8_t h1, h2;
#pragma unroll
            for (int j = 0; j < 8; ++j) {
                float x10 = __fmul_rn(p[j], 1024.0f);        // exact pow2 scale
                _Float16 g1 = (_Float16)x10;
                h1[j] = g1;
                h2[j] = (_Float16)(__fmul_rn(__fsub_rn(x10, (float)g1), 2048.0f));
            }
            const int base = t * 8192 + 128 * quad + 8 * l16;
            *(half8_t*)(ef + base + 512 * (ch * 4 + ct))       = h1;
            *(half8_t*)(ef + base + 512 * ((2 + ch) * 4 + ct)) = h2;
        }
}

// ---- main: 128 rows x 512 codes per block, barrier-free K-loop ----
__global__ __launch_bounds__(BLOCK, 3) void vq_main(
    const float* __restrict__ z, const _Float16* __restrict__ ef,
    const float* __restrict__ cn, u64* __restrict__ keys) {
    __shared__ __align__(16) float zf[BR * 68];
    __shared__ float sS[BR];
    __shared__ float sCn[512];

    const int tid  = threadIdx.x;
    const int lane = tid & 63;
    const int wv   = tid >> 6;
    const int quad = lane >> 4;
    const int l16  = lane & 15;
    const int rb = blockIdx.x >> 1, ks = blockIdx.x & 1;
    const long rowbase = (long)rb * BR;
    const int kb0 = ks * 512;

    // stage z (coalesced) + this slice's code norms
    const float4* gz = (const float4*)(z + rowbase * D);
#pragma unroll
    for (int i = 0; i < 8; ++i) {
        int idx4 = i * BLOCK + tid;
        int r = idx4 >> 4, j = idx4 & 15;
        *(float4*)(zf + r * 68 + j * 4) = gz[idx4];
    }
    sCn[tid]       = cn[kb0 + tid];
    sCn[tid + 256] = cn[kb0 + tid + 256];
    __syncthreads();

    if (tid < BR) sS[tid] = np_sumsq64_p(zf + tid * 68);

    // A-frags (register-resident f16 splits), rows wv*32 .. wv*32+31
    half8_t a1[2][2], a2[2][2];
#pragma unroll
    for (int rt = 0; rt < 2; ++rt) {
        const int row = wv * 32 + rt * 16 + l16;
#pragma unroll
        for (int ch = 0; ch < 2; ++ch) {
            const float* p = zf + row * 68 + ch * 32 + quad * 8;
            float4 f0 = *(const float4*)(p);
            float4 f1 = *(const float4*)(p + 4);
            float xs[8] = {f0.x, f0.y, f0.z, f0.w, f1.x, f1.y, f1.z, f1.w};
#pragma unroll
            for (int j = 0; j < 8; ++j) {
                _Float16 h1 = (_Float16)xs[j];
                a1[rt][ch][j] = h1;
                a2[rt][ch][j] =
                    (_Float16)(__fmul_rn(__fsub_rn(xs[j], (float)h1), 2048.0f));
            }
        }
    }
    __syncthreads();   // sS visible

    float myS[2][4];
#pragma unroll
    for (int rt = 0; rt < 2; ++rt)
#pragma unroll
        for (int r = 0; r < 4; ++r)
            myS[rt][r] = sS[wv * 32 + rt * 16 + quad * 4 + r];

    float bv[2][4];
    int   bi[2][4];
#pragma unroll
    for (int rt = 0; rt < 2; ++rt)
#pragma unroll
        for (int r = 0; r < 4; ++r) { bv[rt][r] = INFINITY; bi[rt][r] = 0; }

    const _Float16* eb = ef + (long)ks * 8 * 8192;

    for (int t = 0; t < 8; ++t) {
        const _Float16* tb = eb + t * 8192 + 8 * lane;
        const int kbase = kb0 + t * 64;
#pragma unroll
        for (int ctp = 0; ctp < 2; ++ctp) {
            half8_t b1[2][2], b2[2][2];   // [ct2][ch], global->VGPR, L2-hot
#pragma unroll
            for (int ct2 = 0; ct2 < 2; ++ct2) {
                const int ct = ctp * 2 + ct2;
#pragma unroll
                for (int ch = 0; ch < 2; ++ch) {
                    b1[ct2][ch] = *(const half8_t*)(tb + 512 * (ch * 4 + ct));
                    b2[ct2][ch] = *(const half8_t*)(tb + 512 * ((2 + ch) * 4 + ct));
                }
            }
#pragma unroll
            for (int rt = 0; rt < 2; ++rt) {
                floatx4 aM[2], aC[2];
#pragma unroll
                for (int c = 0; c < 2; ++c) {
                    aM[c] = (floatx4){0.f, 0.f, 0.f, 0.f};
                    aC[c] = (floatx4){0.f, 0.f, 0.f, 0.f};
                }
#pragma unroll
                for (int ch = 0; ch < 2; ++ch)
#pragma unroll
                    for (int c = 0; c < 2; ++c) {
                        aM[c] = __builtin_amdgcn_mfma_f32_16x16x32_f16(
                            a1[rt][ch], b1[c][ch], aM[c], 0, 0, 0);
                        aC[c] = __builtin_amdgcn_mfma_f32_16x16x32_f16(
                            a1[rt][ch], b2[c][ch], aC[c], 0, 0, 0);
                        aC[c] = __builtin_amdgcn_mfma_f32_16x16x32_f16(
                            a2[rt][ch], b1[c][ch], aC[c], 0, 0, 0);
                    }
                // dist + argmin; C layout col=l16, row=quad*4+reg
#pragma unroll
                for (int c = 0; c < 2; ++c) {
                    const int ct = ctp * 2 + c;
                    const float cnv = sCn[t * 64 + ct * 16 + l16];
                    const int kg = kbase + ct * 16 + l16;
#pragma unroll
                    for (int r = 0; r < 4; ++r) {
                        float ds = fmaf(aC[c][r], 0x1p-11f, aM[c][r]); // 1024*d
                        float t2 = __fmul_rn(ds, 0x1p-9f);             // 2d exact
                        float dist = __fadd_rn(__fsub_rn(myS[rt][r], t2), cnv);
                        if (dist < bv[rt][r]) { bv[rt][r] = dist; bi[rt][r] = kg; }
                    }
                }
            }
        }
    }

    // reduce over the 16 code-columns, then merge slices via u64 atomicMin
#pragma unroll
    for (int rt = 0; rt < 2; ++rt)
#pragma unroll
        for (int r = 0; r < 4; ++r) {
            float v = bv[rt][r];
            int   x = bi[rt][r];
#pragma unroll
            for (int off = 1; off <= 8; off <<= 1) {
                float ov = __shfl_xor(v, off);
                int   ox = __shfl_xor(x, off);
                if (ov < v || (ov == v && ox < x)) { v = ov; x = ox; }
            }
            if (l16 == 0) {
                const long row = rowbase + wv * 32 + rt * 16 + quad * 4 + r;
                u64 key = ((u64)__float_as_uint(v) << 32) | (unsigned)x;
                atomicMin(&keys[row], key);
            }
        }
}

// ---- resolve: unpack keys, write idx + gather z_q ----
__global__ void vq_resolve(const float* __restrict__ cb,
                           const u64* __restrict__ keys,
                           float* __restrict__ zq, float* __restrict__ idx_out) {
    const int gid = blockIdx.x * BLOCK + threadIdx.x;
    const int row = gid >> 4, j = gid & 15;
    const unsigned k = (unsigned)(keys[row] & 0xFFFFFFFFu);
    ((float4*)zq)[gid] = ((const float4*)cb)[(long)k * 16 + j];
    if (j == 0) idx_out[row] = (float)k;
}

extern "C" void kernel_launch(void* const* d_in, const int* in_sizes, int n_in,
                              void* d_out, int out_size, void* d_ws, size_t ws_size,
                              hipStream_t stream) {
    const float* z  = (const float*)d_in[0];
    const float* cb = (const float*)d_in[1];

    const int n_rows = in_sizes[0] / D;                 // 65536
    float* zq      = (float*)d_out;
    float* idx_out = zq + (long)n_rows * D;

    u64*      ws_keys = (u64*)((char*)d_ws + WS_KEYS_OFF);
    float*    ws_cn   = (float*)((char*)d_ws + WS_CN_OFF);
    _Float16* ws_ef   = (_Float16*)((char*)d_ws + WS_EF_OFF);

    hipMemsetAsync(ws_keys, 0xFF, (size_t)n_rows * sizeof(u64), stream);
    vq_pre<<<K / 64, 64, 0, stream>>>(cb, ws_cn, ws_ef);
    vq_main<<<(n_rows / BR) * 2, BLOCK, 0, stream>>>(z, ws_ef, ws_cn, ws_keys);
    vq_resolve<<<(n_rows * 16) / BLOCK, BLOCK, 0, stream>>>(cb, ws_keys, zq, idx_out);
}

// Round 6
// 111.545 us; speedup vs baseline: 1.7738x; 1.0127x over previous
//
#include <hip/hip_runtime.h>
#include <hip/hip_bf16.h>
#include <math.h>

// VectorQuantizer: z [65536 x 64] fp32, codebook [1024 x 64] fp32.
// dist = (||z||^2 - 2 z.e) + ||e||^2, argmin_k, first-occurrence ties.
// Numerics identical to R4/R5 (passed, absmax 0): exact np pairwise sumsq for
// S/cn; d via f16 split-2 3-pass MFMA (err ~1e-8 << absorption bin 7.6e-6);
// dist = (S - 2d) + cn with explicit __f*_rn; (dist,k) lexicographic merge.
//
// R5 post-mortem: B-frag L2 traffic = waves x 128KB = 512 MB (~15us/XCD wall)
// + <2 waves/SIMD -> latency-dominated 46us. R6: 64 rows/WAVE (4 rt, A-frags
// 64 VGPR register-resident), 1-wave blocks (64 thr), K-split 2 -> B traffic
// 256 MB, 2048 waves = full residency (8 blocks/CU, LDS 19.7KB). Per tile:
// 4 b128 loads feed 24 MFMA + ~90 VALU-ops/lane -> latency hidden by ILP.

#define D      64
#define K      1024
#define BR     64               // rows per block (= per wave)
#define BLOCK  64

typedef _Float16 half8_t __attribute__((ext_vector_type(8)));
typedef float    floatx4 __attribute__((ext_vector_type(4)));
typedef unsigned long long u64;

// ws layout
#define WS_KEYS_OFF  0            // u64[65536]          (512 KB)
#define WS_CN_OFF    524288       // float[1024]         (4 KB)
#define WS_EF_OFF    528384       // _Float16[131072]    (256 KB)
// per 64-code tile t: 8192 halves; frag (spl,ch,ct) at half-offset
//   t*8192 + 512*((spl*2+ch)*4+ct) + 8*lane

// numpy pairwise sumsq (n=64): 8 stride-8 accs of fl(x^2), tree combine.
__device__ __forceinline__ float np_sumsq64_p(const float* __restrict__ x) {
    float r[8];
    {
        float4 v0 = *(const float4*)(x);
        float4 v1 = *(const float4*)(x + 4);
        r[0] = __fmul_rn(v0.x, v0.x); r[1] = __fmul_rn(v0.y, v0.y);
        r[2] = __fmul_rn(v0.z, v0.z); r[3] = __fmul_rn(v0.w, v0.w);
        r[4] = __fmul_rn(v1.x, v1.x); r[5] = __fmul_rn(v1.y, v1.y);
        r[6] = __fmul_rn(v1.z, v1.z); r[7] = __fmul_rn(v1.w, v1.w);
    }
#pragma unroll
    for (int i = 8; i < 64; i += 8) {
        float4 v0 = *(const float4*)(x + i);
        float4 v1 = *(const float4*)(x + i + 4);
        r[0] = __fadd_rn(r[0], __fmul_rn(v0.x, v0.x));
        r[1] = __fadd_rn(r[1], __fmul_rn(v0.y, v0.y));
        r[2] = __fadd_rn(r[2], __fmul_rn(v0.z, v0.z));
        r[3] = __fadd_rn(r[3], __fmul_rn(v0.w, v0.w));
        r[4] = __fadd_rn(r[4], __fmul_rn(v1.x, v1.x));
        r[5] = __fadd_rn(r[5], __fmul_rn(v1.y, v1.y));
        r[6] = __fadd_rn(r[6], __fmul_rn(v1.z, v1.z));
        r[7] = __fadd_rn(r[7], __fmul_rn(v1.w, v1.w));
    }
    return __fadd_rn(__fadd_rn(__fadd_rn(r[0], r[1]), __fadd_rn(r[2], r[3])),
                     __fadd_rn(__fadd_rn(r[4], r[5]), __fadd_rn(r[6], r[7])));
}

// ---- precompute: code norms + f16 split-2 B-frags in MFMA lane order ----
__global__ void vq_pre(const float* __restrict__ cb, float* __restrict__ cn,
                       _Float16* __restrict__ ef) {
    const int k = blockIdx.x * 64 + threadIdx.x;
    if (k >= K) return;
    cn[k] = np_sumsq64_p(cb + (long)k * D);
    const int t = k >> 6, ct = (k >> 4) & 3, l16 = k & 15;
#pragma unroll
    for (int ch = 0; ch < 2; ++ch)
#pragma unroll
        for (int quad = 0; quad < 4; ++quad) {
            const float* p = cb + (long)k * D + ch * 32 + quad * 8;
            half8_t h1, h2;
#pragma unroll
            for (int j = 0; j < 8; ++j) {
                float x10 = __fmul_rn(p[j], 1024.0f);        // exact pow2 scale
                _Float16 g1 = (_Float16)x10;
                h1[j] = g1;
                h2[j] = (_Float16)(__fmul_rn(__fsub_rn(x10, (float)g1), 2048.0f));
            }
            const int base = t * 8192 + 128 * quad + 8 * l16;
            *(half8_t*)(ef + base + 512 * (ch * 4 + ct))       = h1;
            *(half8_t*)(ef + base + 512 * ((2 + ch) * 4 + ct)) = h2;
        }
}

// ---- main: 64 rows x 512 codes per 1-wave block ----
__global__ __launch_bounds__(BLOCK, 2) void vq_main(
    const float* __restrict__ z, const _Float16* __restrict__ ef,
    const float* __restrict__ cn, u64* __restrict__ keys) {
    __shared__ __align__(16) float zf[BR * 68];
    __shared__ float sS[BR];
    __shared__ float sCn[512];

    const int lane = threadIdx.x;
    const int quad = lane >> 4;
    const int l16  = lane & 15;
    const int rb = blockIdx.x >> 1, ks = blockIdx.x & 1;
    const long rowbase = (long)rb * BR;
    const int kb0 = ks * 512;

    // stage z (coalesced, 16 float4/lane) + this slice's code norms
    const float4* gz = (const float4*)(z + rowbase * D);
#pragma unroll
    for (int i = 0; i < 16; ++i) {
        int idx4 = i * BLOCK + lane;
        int r = idx4 >> 4, j = idx4 & 15;
        *(float4*)(zf + r * 68 + j * 4) = gz[idx4];
    }
#pragma unroll
    for (int i = 0; i < 8; ++i) sCn[i * 64 + lane] = cn[kb0 + i * 64 + lane];
    __syncthreads();

    // row norms (exact np chain), one row per lane
    sS[lane] = np_sumsq64_p(zf + lane * 68);

    // A-frags: register-resident f16 splits; rt tile rows rt*16 + l16
    half8_t a1[4][2], a2[4][2];
#pragma unroll
    for (int rt = 0; rt < 4; ++rt) {
        const int row = rt * 16 + l16;
#pragma unroll
        for (int ch = 0; ch < 2; ++ch) {
            const float* p = zf + row * 68 + ch * 32 + quad * 8;
            float4 f0 = *(const float4*)(p);
            float4 f1 = *(const float4*)(p + 4);
            float xs[8] = {f0.x, f0.y, f0.z, f0.w, f1.x, f1.y, f1.z, f1.w};
#pragma unroll
            for (int j = 0; j < 8; ++j) {
                _Float16 h1 = (_Float16)xs[j];
                a1[rt][ch][j] = h1;
                a2[rt][ch][j] =
                    (_Float16)(__fmul_rn(__fsub_rn(xs[j], (float)h1), 2048.0f));
            }
        }
    }
    __syncthreads();   // sS visible

    float myS[4][4];
#pragma unroll
    for (int rt = 0; rt < 4; ++rt)
#pragma unroll
        for (int r = 0; r < 4; ++r)
            myS[rt][r] = sS[rt * 16 + quad * 4 + r];

    float bv[4][4];
    int   bi[4][4];
#pragma unroll
    for (int rt = 0; rt < 4; ++rt)
#pragma unroll
        for (int r = 0; r < 4; ++r) { bv[rt][r] = INFINITY; bi[rt][r] = 0; }

    const _Float16* eb = ef + (long)ks * 8 * 8192;

    for (int t = 0; t < 8; ++t) {
        const _Float16* tb = eb + t * 8192 + 8 * lane;
        const int kbase = kb0 + t * 64;
#pragma unroll
        for (int ct = 0; ct < 4; ++ct) {
            half8_t b1[2], b2[2];          // global->VGPR, L2-hot, coalesced
#pragma unroll
            for (int ch = 0; ch < 2; ++ch) {
                b1[ch] = *(const half8_t*)(tb + 512 * (ch * 4 + ct));
                b2[ch] = *(const half8_t*)(tb + 512 * ((2 + ch) * 4 + ct));
            }
            const float cnv = sCn[t * 64 + ct * 16 + l16];
            const int kg = kbase + ct * 16 + l16;
#pragma unroll
            for (int rt = 0; rt < 4; ++rt) {
                floatx4 aM = (floatx4){0.f, 0.f, 0.f, 0.f};
                floatx4 aC = (floatx4){0.f, 0.f, 0.f, 0.f};
                aM = __builtin_amdgcn_mfma_f32_16x16x32_f16(a1[rt][0], b1[0], aM, 0, 0, 0);
                aM = __builtin_amdgcn_mfma_f32_16x16x32_f16(a1[rt][1], b1[1], aM, 0, 0, 0);
                aC = __builtin_amdgcn_mfma_f32_16x16x32_f16(a1[rt][0], b2[0], aC, 0, 0, 0);
                aC = __builtin_amdgcn_mfma_f32_16x16x32_f16(a1[rt][1], b2[1], aC, 0, 0, 0);
                aC = __builtin_amdgcn_mfma_f32_16x16x32_f16(a2[rt][0], b1[0], aC, 0, 0, 0);
                aC = __builtin_amdgcn_mfma_f32_16x16x32_f16(a2[rt][1], b1[1], aC, 0, 0, 0);
                // C layout: col=l16 (code), row=quad*4+r (z-row in tile)
#pragma unroll
                for (int r = 0; r < 4; ++r) {
                    float ds = fmaf(aC[r], 0x1p-11f, aM[r]);   // 1024*d
                    float t2 = __fmul_rn(ds, 0x1p-9f);         // 2d, exact pow2
                    float dist = __fadd_rn(__fsub_rn(myS[rt][r], t2), cnv);
                    if (dist < bv[rt][r]) { bv[rt][r] = dist; bi[rt][r] = kg; }
                }
            }
        }
    }

    // reduce over the 16 code-columns, then merge k-slices via u64 atomicMin
#pragma unroll
    for (int rt = 0; rt < 4; ++rt)
#pragma unroll
        for (int r = 0; r < 4; ++r) {
            float v = bv[rt][r];
            int   x = bi[rt][r];
#pragma unroll
            for (int off = 1; off <= 8; off <<= 1) {
                float ov = __shfl_xor(v, off);
                int   ox = __shfl_xor(x, off);
                if (ov < v || (ov == v && ox < x)) { v = ov; x = ox; }
            }
            if (l16 == 0) {
                const long row = rowbase + rt * 16 + quad * 4 + r;
                u64 key = ((u64)__float_as_uint(v) << 32) | (unsigned)x;
                atomicMin(&keys[row], key);
            }
        }
}

// ---- resolve: unpack keys, write idx + gather z_q ----
__global__ void vq_resolve(const float* __restrict__ cb,
                           const u64* __restrict__ keys,
                           float* __restrict__ zq, float* __restrict__ idx_out) {
    const int gid = blockIdx.x * 256 + threadIdx.x;
    const int row = gid >> 4, j = gid & 15;
    const unsigned k = (unsigned)(keys[row] & 0xFFFFFFFFu);
    ((float4*)zq)[gid] = ((const float4*)cb)[(long)k * 16 + j];
    if (j == 0) idx_out[row] = (float)k;
}

extern "C" void kernel_launch(void* const* d_in, const int* in_sizes, int n_in,
                              void* d_out, int out_size, void* d_ws, size_t ws_size,
                              hipStream_t stream) {
    const float* z  = (const float*)d_in[0];
    const float* cb = (const float*)d_in[1];

    const int n_rows = in_sizes[0] / D;                 // 65536
    float* zq      = (float*)d_out;
    float* idx_out = zq + (long)n_rows * D;

    u64*      ws_keys = (u64*)((char*)d_ws + WS_KEYS_OFF);
    float*    ws_cn   = (float*)((char*)d_ws + WS_CN_OFF);
    _Float16* ws_ef   = (_Float16*)((char*)d_ws + WS_EF_OFF);

    hipMemsetAsync(ws_keys, 0xFF, (size_t)n_rows * sizeof(u64), stream);
    vq_pre<<<K / 64, 64, 0, stream>>>(cb, ws_cn, ws_ef);
    vq_main<<<(n_rows / BR) * 2, BLOCK, 0, stream>>>(z, ws_ef, ws_cn, ws_keys);
    vq_resolve<<<(n_rows * 16) / 256, 256, 0, stream>>>(cb, ws_keys, zq, idx_out);
}